// Round 1
// baseline (387.222 us; speedup 1.0000x reference)
//
#include <hip/hip_runtime.h>

// ClusteringLoss on MI355X — fused streaming stencil + reduction.
// B=8, K=8, H=W=1024. Memory-bound: ~288 MiB ideal read -> ~48 us floor @6.3TB/s.

constexpr int Bsz  = 8;
constexpr int Kc   = 8;
constexpr int H    = 1024;
constexpr int W    = 1024;
constexpr int ROWS = 8;     // rows per block; halo overhead = 1/ROWS = 12.5%
constexpr int TPB  = 256;   // each thread covers 4 columns (float4); 256*4 = W

#define GAMMA_F    10.0f
#define EPS_SQRT_F 1e-24f

__device__ __forceinline__ float wedge(float c, float dn, float rt,
                                       float inv_sx, float inv_sy, float smin) {
    // c = I[i,j], dn = I[i+1,j] (clamped), rt = I[i,j+1] (clamped)
    float dx = (dn - c) * inv_sx;
    float dy = (rt - c) * inv_sy;
    float gn2 = dx * dx + dy * dy;
    float g = sqrtf(fmaxf(gn2, EPS_SQRT_F));
    return 1.0f / (1.0f + GAMMA_F * g * smin);
}

__device__ __forceinline__ void accum(float pc, float pd, float pr, float w,
                                      float& nom, float& den) {
    float lap = (pd - pc) + (pr - pc);          // p_xp + p_yp
    nom = fmaf(pc, fmaf(w, lap, pc), nom);      // pc*(pc + w*lap)
    den = fmaf(pc, fmaf(2.0f, w, 1.0f), den);   // pc*(1 + 2w)
}

__global__ __launch_bounds__(TPB) void cl_main(const float* __restrict__ I,
                                               const float* __restrict__ spacing,
                                               const float* __restrict__ P,
                                               double* __restrict__ ws) {
    const int t  = threadIdx.x;
    const int j0 = t * 4;
    const int b  = blockIdx.y;
    const int r0 = blockIdx.x * ROWS;

    const float sx = spacing[0], sy = spacing[1];
    const float inv_sx = 1.0f / sx, inv_sy = 1.0f / sy;
    const float smin = fminf(sx, sy);

    const int jr = (j0 + 4 < W) ? (j0 + 4) : (W - 1);  // right-halo column (clamped)

    const float* Ib = I + (size_t)b * H * W;
    const float* Pb = P + (size_t)b * Kc * H * W;

    // ---- register carry: current row of I and all K channels of p ----
    float4 cI  = *(const float4*)(Ib + (size_t)r0 * W + j0);
    float  cIr = Ib[(size_t)r0 * W + jr];
    float4 cp[Kc];
    float  cpr[Kc];
#pragma unroll
    for (int k = 0; k < Kc; ++k) {
        const float* Pk = Pb + (size_t)k * H * W;
        cp[k]  = *(const float4*)(Pk + (size_t)r0 * W + j0);
        cpr[k] = Pk[(size_t)r0 * W + jr];
    }

    float nom[Kc], den[Kc];
#pragma unroll
    for (int k = 0; k < Kc; ++k) { nom[k] = 0.0f; den[k] = 0.0f; }

    for (int i = r0; i < r0 + ROWS; ++i) {
        const int inext = (i + 1 < H) ? (i + 1) : (H - 1);
        const float4 nI  = *(const float4*)(Ib + (size_t)inext * W + j0);
        const float  nIr = Ib[(size_t)inext * W + jr];

        // per-pixel edge weights (shared across all K channels)
        const float w0 = wedge(cI.x, nI.x, cI.y, inv_sx, inv_sy, smin);
        const float w1 = wedge(cI.y, nI.y, cI.z, inv_sx, inv_sy, smin);
        const float w2 = wedge(cI.z, nI.z, cI.w, inv_sx, inv_sy, smin);
        const float w3 = wedge(cI.w, nI.w, cIr,  inv_sx, inv_sy, smin);

#pragma unroll
        for (int k = 0; k < Kc; ++k) {
            const float* Pk = Pb + (size_t)k * H * W;
            const float4 np  = *(const float4*)(Pk + (size_t)inext * W + j0);
            const float  npr = Pk[(size_t)inext * W + jr];

            accum(cp[k].x, np.x, cp[k].y, w0, nom[k], den[k]);
            accum(cp[k].y, np.y, cp[k].z, w1, nom[k], den[k]);
            accum(cp[k].z, np.z, cp[k].w, w2, nom[k], den[k]);
            accum(cp[k].w, np.w, cpr[k],  w3, nom[k], den[k]);

            cp[k]  = np;
            cpr[k] = npr;
        }
        cI  = nI;
        cIr = nIr;
    }

    // ---- reduction: wave shuffle -> LDS -> one double atomic per accumulator ----
    __shared__ float red[4][2 * Kc];  // 4 waves x (8 nom + 8 den)
    const int lane = t & 63;
    const int wave = t >> 6;

#pragma unroll
    for (int k = 0; k < Kc; ++k) {
        float n = nom[k], d = den[k];
#pragma unroll
        for (int off = 32; off > 0; off >>= 1) {
            n += __shfl_down(n, off, 64);
            d += __shfl_down(d, off, 64);
        }
        if (lane == 0) {
            red[wave][k]      = n;
            red[wave][Kc + k] = d;
        }
    }
    __syncthreads();

    if (t < 2 * Kc) {
        float s = red[0][t] + red[1][t] + red[2][t] + red[3][t];
        const int k = t & (Kc - 1);
        const int which = t >> 3;  // 0 = nom, 1 = den
        atomicAdd(&ws[(size_t)(b * Kc + k) * 2 + which], (double)s);
    }
}

__global__ void cl_final(const double* __restrict__ ws, float* __restrict__ out) {
    const int t = threadIdx.x;  // 64 threads
    double c = 0.0;
    if (t < Bsz * Kc) {
        const double n = ws[(size_t)t * 2 + 0];
        const double d = ws[(size_t)t * 2 + 1];
        c = n / d;
    }
#pragma unroll
    for (int off = 32; off > 0; off >>= 1) c += __shfl_down(c, off, 64);
    if (t == 0) out[0] = (float)((double)(Bsz * Kc) - c);
}

extern "C" void kernel_launch(void* const* d_in, const int* in_sizes, int n_in,
                              void* d_out, int out_size, void* d_ws, size_t ws_size,
                              hipStream_t stream) {
    const float* I       = (const float*)d_in[0];  // (8,1,1024,1024)
    const float* spacing = (const float*)d_in[1];  // (2,)
    const float* P       = (const float*)d_in[2];  // (8,8,1024,1024)
    float* out = (float*)d_out;
    double* ws = (double*)d_ws;  // 64 x (nom, den) doubles = 1 KiB

    hipMemsetAsync(d_ws, 0, (size_t)Bsz * Kc * 2 * sizeof(double), stream);

    dim3 grid(H / ROWS, Bsz);
    cl_main<<<grid, TPB, 0, stream>>>(I, spacing, P, ws);
    cl_final<<<1, 64, 0, stream>>>(ws, out);
}